// Round 2
// baseline (484.735 us; speedup 1.0000x reference)
//
#include <hip/hip_runtime.h>
#include <math.h>

#define NENT 500000
#define DIMK 64
#define LHOP 2
#define BB 2048
#define MM 64

// workspace layout (floats)
#define OFF_W1T   0        // [128][64]
#define OFF_W2T   8192     // [64][64]
#define OFF_WAGGT 12288    // [192][64]
#define OFF_EP    24576    // [2][3][B][64]
// total floats: 24576 + 786432 = 811008 (~3.2 MB)

__device__ __forceinline__ float sigmoidf_(float x) {
    return 1.0f / (1.0f + expf(-x));
}

__global__ void transpose_weights(const float* __restrict__ w1,
                                  const float* __restrict__ w2,
                                  const float* __restrict__ wagg,
                                  float* __restrict__ ws) {
    int t = blockIdx.x * blockDim.x + threadIdx.x;
    int stride = gridDim.x * blockDim.x;
    // w1: (64,128) -> w1T[k][j] = w1[j*128+k], 8192 elems
    for (int i = t; i < 8192; i += stride) {
        int k = i >> 6, j = i & 63;
        ws[OFF_W1T + i] = w1[j * 128 + k];
    }
    // w2: (64,64) -> w2T[k][j] = w2[j*64+k]
    for (int i = t; i < 4096; i += stride) {
        int k = i >> 6, j = i & 63;
        ws[OFF_W2T + i] = w2[j * 64 + k];
    }
    // wagg: (64,192) -> waggT[k][j] = wagg[j*192+k]
    for (int i = t; i < 12288; i += stride) {
        int k = i >> 6, j = i & 63;
        ws[OFF_WAGGT + i] = wagg[j * 192 + k];
    }
}

// hop-0: e0[side][b][d] = mean_m table[ent[b][m]][d]
__global__ __launch_bounds__(256) void hop0_kernel(
    const float* __restrict__ ent_emb, const float* __restrict__ rec_emb,
    const int* __restrict__ u_ent, const int* __restrict__ v_ent,
    float* __restrict__ e_parts) {
    int wt = blockIdx.x * 4 + (threadIdx.x >> 6); // 0..4095
    int lane = threadIdx.x & 63;
    int b = wt & 2047;
    int side = wt >> 11;
    const int* ent = side ? v_ent : u_ent;
    const float* tab = side ? ent_emb : rec_emb;
    float acc = 0.0f;
#pragma unroll 8
    for (int m = 0; m < 64; m++) {
        int em = ent[b * 64 + m]; // wave-uniform -> s_load
        acc += tab[(size_t)em * 64 + lane];
    }
    e_parts[((side * 3 + 0) * BB + b) * 64 + lane] = acc * (1.0f / 64.0f);
}

// one wave per (side, l, b): full DNN for 64 neighbors (lane=m),
// wave softmax, then weighted tail aggregation.
__global__ __launch_bounds__(256) void attn_kernel(
    const float* __restrict__ ent_emb, const float* __restrict__ rel_emb,
    const float* __restrict__ b1, const float* __restrict__ b2,
    const float* __restrict__ w3, const float* __restrict__ b3,
    const int* __restrict__ u_heads, const int* __restrict__ u_rels,
    const int* __restrict__ u_tails,
    const int* __restrict__ v_heads, const int* __restrict__ v_rels,
    const int* __restrict__ v_tails,
    const float* __restrict__ ws, float* __restrict__ e_parts) {
    int wt = blockIdx.x * 4 + (threadIdx.x >> 6); // 0..8191
    int lane = threadIdx.x & 63;
    int b = wt & 2047;
    int l = (wt >> 11) & 1;
    int side = wt >> 12;

    const int* heads = side ? v_heads : u_heads;
    const int* rels  = side ? v_rels  : u_rels;
    const int* tails = side ? v_tails : u_tails;
    int base = (l * BB + b) * MM + lane;
    int hidx = heads[base];
    int ridx = rels[base];
    int tidx = tails[base];

    const float* w1T = ws + OFF_W1T;
    const float* w2T = ws + OFF_W2T;

    float y1[64];
#pragma unroll
    for (int j = 0; j < 64; j++) y1[j] = b1[j];

    // layer 1, first half: h (x[0..63])
    {
        const float4* hrow = (const float4*)(ent_emb + (size_t)hidx * 64);
#pragma unroll 1
        for (int kc = 0; kc < 8; kc++) {
            float4 xa = hrow[kc * 2 + 0];
            float4 xb = hrow[kc * 2 + 1];
            float xs[8] = {xa.x, xa.y, xa.z, xa.w, xb.x, xb.y, xb.z, xb.w};
#pragma unroll
            for (int ku = 0; ku < 8; ku++) {
                const float* wrow = w1T + (kc * 8 + ku) * 64; // uniform -> s_load
#pragma unroll
                for (int j = 0; j < 64; j++)
                    y1[j] = fmaf(xs[ku], wrow[j], y1[j]);
            }
        }
    }
    // layer 1, second half: r (x[64..127])
    {
        const float4* rrow = (const float4*)(rel_emb + (size_t)ridx * 64);
#pragma unroll 1
        for (int kc = 0; kc < 8; kc++) {
            float4 xa = rrow[kc * 2 + 0];
            float4 xb = rrow[kc * 2 + 1];
            float xs[8] = {xa.x, xa.y, xa.z, xa.w, xb.x, xb.y, xb.z, xb.w};
#pragma unroll
            for (int ku = 0; ku < 8; ku++) {
                const float* wrow = w1T + (64 + kc * 8 + ku) * 64;
#pragma unroll
                for (int j = 0; j < 64; j++)
                    y1[j] = fmaf(xs[ku], wrow[j], y1[j]);
            }
        }
    }
#pragma unroll
    for (int j = 0; j < 64; j++) y1[j] = fmaxf(y1[j], 0.0f);

    // layer 2 (fully unrolled 64x64; y1 static-indexed -> stays in regs)
    float y2[64];
#pragma unroll
    for (int j = 0; j < 64; j++) y2[j] = b2[j];
#pragma unroll
    for (int k = 0; k < 64; k++) {
#pragma unroll
        for (int j = 0; j < 64; j++)
            y2[j] = fmaf(y1[k], w2T[k * 64 + j], y2[j]);
    }
#pragma unroll
    for (int j = 0; j < 64; j++) y2[j] = fmaxf(y2[j], 0.0f);

    // layer 3
    float s = b3[0];
#pragma unroll
    for (int j = 0; j < 64; j++) s = fmaf(y2[j], w3[j], s);
    float pi = sigmoidf_(s);

    // softmax across the 64 neighbors (one per lane)
    float mx = pi;
#pragma unroll
    for (int o = 32; o > 0; o >>= 1) mx = fmaxf(mx, __shfl_xor(mx, o));
    float e = expf(pi - mx);
    float sum = e;
#pragma unroll
    for (int o = 32; o > 0; o >>= 1) sum += __shfl_xor(sum, o);
    float p = e / sum;

    // weighted tail aggregation: a[d] = sum_m p_m * ent_emb[tail_m][d]
    float acc = 0.0f;
#pragma unroll 8
    for (int m = 0; m < 64; m++) {
        int  tm = __shfl(tidx, m);
        float pm = __shfl(p, m);
        acc = fmaf(pm, ent_emb[(size_t)tm * 64 + lane], acc);
    }
    e_parts[((side * 3 + (l + 1)) * BB + b) * 64 + lane] = acc;
}

// final: per b, user/item agg MLP + dot + sigmoid
__global__ __launch_bounds__(256) void final_kernel(
    const float* __restrict__ bagg, const float* __restrict__ ws,
    float* __restrict__ out) {
    const float* waggT = ws + OFF_WAGGT;
    const float* ep = ws + OFF_EP;
    int b = blockIdx.x * 4 + (threadIdx.x >> 6);
    int lane = threadIdx.x & 63;
    float eu[3], ev[3];
#pragma unroll
    for (int c = 0; c < 3; c++) {
        eu[c] = ep[((0 * 3 + c) * BB + b) * 64 + lane];
        ev[c] = ep[((1 * 3 + c) * BB + b) * 64 + lane];
    }
    float us = bagg[lane], it = bagg[lane];
#pragma unroll
    for (int k = 0; k < 192; k++) {
        float w = waggT[k * 64 + lane]; // coalesced per-lane
        us = fmaf(__shfl(eu[k >> 6], k & 63), w, us);
        it = fmaf(__shfl(ev[k >> 6], k & 63), w, it);
    }
    us = sigmoidf_(us);
    it = sigmoidf_(it);
    float prod = us * it;
#pragma unroll
    for (int o = 32; o > 0; o >>= 1) prod += __shfl_xor(prod, o);
    if (lane == 0) out[b] = sigmoidf_(prod);
}

extern "C" void kernel_launch(void* const* d_in, const int* in_sizes, int n_in,
                              void* d_out, int out_size, void* d_ws, size_t ws_size,
                              hipStream_t stream) {
    const float* ent_emb = (const float*)d_in[0];
    const float* rec_emb = (const float*)d_in[1];
    const float* rel_emb = (const float*)d_in[2];
    const float* w1   = (const float*)d_in[3];
    const float* b1   = (const float*)d_in[4];
    const float* w2   = (const float*)d_in[5];
    const float* b2   = (const float*)d_in[6];
    const float* w3   = (const float*)d_in[7];
    const float* b3   = (const float*)d_in[8];
    const float* wagg = (const float*)d_in[9];
    const float* bagg = (const float*)d_in[10];
    const int* u_ent   = (const int*)d_in[11];
    const int* u_heads = (const int*)d_in[12];
    const int* u_rels  = (const int*)d_in[13];
    const int* u_tails = (const int*)d_in[14];
    const int* v_ent   = (const int*)d_in[15];
    const int* v_heads = (const int*)d_in[16];
    const int* v_rels  = (const int*)d_in[17];
    const int* v_tails = (const int*)d_in[18];

    float* ws = (float*)d_ws;
    float* e_parts = ws + OFF_EP;
    float* out = (float*)d_out;

    transpose_weights<<<32, 256, 0, stream>>>(w1, w2, wagg, ws);
    hop0_kernel<<<1024, 256, 0, stream>>>(ent_emb, rec_emb, u_ent, v_ent, e_parts);
    attn_kernel<<<2048, 256, 0, stream>>>(ent_emb, rel_emb, b1, b2, w3, b3,
                                          u_heads, u_rels, u_tails,
                                          v_heads, v_rels, v_tails,
                                          ws, e_parts);
    final_kernel<<<512, 256, 0, stream>>>(bagg, ws, out);
}

// Round 4
// 326.454 us; speedup vs baseline: 1.4848x; 1.4848x over previous
//
#include <hip/hip_runtime.h>
#include <math.h>

#define BB 2048
#define MM 64

typedef __attribute__((ext_vector_type(8))) short short8;
typedef __attribute__((ext_vector_type(4))) float float4v;
typedef __attribute__((ext_vector_type(4))) int int4v;

union Frag { int4v v; short8 s; int u[4]; };

// workspace layout in 4-byte words:
#define OFF_A1    0        // w1 A-frags: [4 tr][4 ks][64 lane][4 u32] = 4096
#define OFF_A2    4096     // w2 A-frags: [4 tr][2 ks][64 lane][4 u32] = 2048
#define OFF_WAGGT 6144     // waggT [192][64] f32 = 12288
#define OFF_EP    18432    // e_parts [2][3][BB][64] f32 = 786432
// total = 804864 words ~= 3.2 MB

__device__ __forceinline__ float sigmoidf_(float x) {
    return 1.0f / (1.0f + expf(-x));
}

__device__ __forceinline__ int pk2(float lo, float hi) {
    int r;
    asm("v_cvt_pk_bf16_f32 %0, %1, %2" : "=v"(r) : "v"(lo), "v"(hi));
    return r;
}

// pack w1/w2 into MFMA A-fragment layout (A row j = lane&15, k = (lane>>4)*8+2r)
// and transpose wagg for the final kernel. 12288 threads.
__global__ __launch_bounds__(256) void prep_kernel(
    const float* __restrict__ w1, const float* __restrict__ w2,
    const float* __restrict__ wagg, int* __restrict__ wsI) {
    int t = blockIdx.x * 256 + threadIdx.x; // 0..12287
    if (t < 4096) { // a1
        int r = t & 3, lane = (t >> 2) & 63, ks = (t >> 8) & 3, tr = t >> 10;
        int j = tr * 16 + (lane & 15);
        int k = ks * 32 + (lane >> 4) * 8 + 2 * r;
        wsI[OFF_A1 + t] = pk2(w1[j * 128 + k], w1[j * 128 + k + 1]);
    }
    if (t < 2048) { // a2
        int r = t & 3, lane = (t >> 2) & 63, ks = (t >> 8) & 1, tr = t >> 9;
        int j = tr * 16 + (lane & 15);
        int k = ks * 32 + (lane >> 4) * 8 + 2 * r;
        wsI[OFF_A2 + t] = pk2(w2[j * 64 + k], w2[j * 64 + k + 1]);
    }
    if (t < 12288) { // waggT[k][j] = wagg[j*192+k]
        int k = t >> 6, j = t & 63;
        ((float*)wsI)[OFF_WAGGT + t] = wagg[j * 192 + k];
    }
}

// hop-0: e0[side][b][d] = mean_m table[ent[b][m]][d]
__global__ __launch_bounds__(256) void hop0_kernel(
    const float* __restrict__ ent_emb, const float* __restrict__ rec_emb,
    const int* __restrict__ u_ent, const int* __restrict__ v_ent,
    float* __restrict__ e_parts) {
    int wt = blockIdx.x * 4 + (threadIdx.x >> 6); // 0..4095
    int lane = threadIdx.x & 63;
    int b = wt & 2047;
    int side = wt >> 11;
    const int* ent = side ? v_ent : u_ent;
    const float* tab = side ? ent_emb : rec_emb;
    float a0 = 0.f, a1 = 0.f, a2 = 0.f, a3 = 0.f;
#pragma unroll 4
    for (int m = 0; m < 64; m += 4) {
        int e0 = ent[b * 64 + m + 0], e1 = ent[b * 64 + m + 1];
        int e2 = ent[b * 64 + m + 2], e3 = ent[b * 64 + m + 3];
        a0 += tab[(size_t)e0 * 64 + lane];
        a1 += tab[(size_t)e1 * 64 + lane];
        a2 += tab[(size_t)e2 * 64 + lane];
        a3 += tab[(size_t)e3 * 64 + lane];
    }
    e_parts[((side * 3 + 0) * BB + b) * 64 + lane] =
        (a0 + a1 + a2 + a3) * (1.0f / 64.0f);
}

// one wave per (side, l, b). MFMA DNN computing Y^T = W * X^T so the
// B-operand column index IS the neighbor m (direct global-load fragments).
__global__ __launch_bounds__(256) void attn_kernel(
    const float* __restrict__ ent_emb, const float* __restrict__ rel_emb,
    const float* __restrict__ b1, const float* __restrict__ b2,
    const float* __restrict__ w3, const float* __restrict__ b3,
    const int* __restrict__ u_heads, const int* __restrict__ u_rels,
    const int* __restrict__ u_tails,
    const int* __restrict__ v_heads, const int* __restrict__ v_rels,
    const int* __restrict__ v_tails,
    const int* __restrict__ wsI, float* __restrict__ e_parts) {
    int lane = threadIdx.x & 63;
    int wt = blockIdx.x * 4 + (threadIdx.x >> 6); // 0..8191
    int b = wt & 2047;
    int l = (wt >> 11) & 1;
    int side = wt >> 12;
    int c = lane & 15, g = lane >> 4;

    const int* heads = side ? v_heads : u_heads;
    const int* rels  = side ? v_rels  : u_rels;
    const int* tails = side ? v_tails : u_tails;
    int base = (l * BB + b) * MM + lane;
    int hidx = heads[base];
    int ridx = rels[base];
    int tidx = tails[base];

    const int4v* a1p = (const int4v*)(wsI + OFF_A1);
    const int4v* a2p = (const int4v*)(wsI + OFF_A2);

    // ---- B fragments of X^T: lane holds col m = tc*16+c, k = g*8+e ----
    Frag bx[4][4]; // [tc][ks], k = ks*32 + g*8 + e; k<64 -> h, else r
#pragma unroll
    for (int tc = 0; tc < 4; tc++) {
        int hn = __shfl(hidx, tc * 16 + c);
        int rn = __shfl(ridx, tc * 16 + c);
        const float4v* hp = (const float4v*)(ent_emb + (size_t)hn * 64 + g * 8);
        const float4v* rp = (const float4v*)(rel_emb + (size_t)rn * 64 + g * 8);
        float4v h0 = hp[0], h1 = hp[1], h2 = hp[8], h3 = hp[9];
        float4v r0 = rp[0], r1 = rp[1], r2 = rp[8], r3 = rp[9];
        bx[tc][0].u[0] = pk2(h0[0], h0[1]); bx[tc][0].u[1] = pk2(h0[2], h0[3]);
        bx[tc][0].u[2] = pk2(h1[0], h1[1]); bx[tc][0].u[3] = pk2(h1[2], h1[3]);
        bx[tc][1].u[0] = pk2(h2[0], h2[1]); bx[tc][1].u[1] = pk2(h2[2], h2[3]);
        bx[tc][1].u[2] = pk2(h3[0], h3[1]); bx[tc][1].u[3] = pk2(h3[2], h3[3]);
        bx[tc][2].u[0] = pk2(r0[0], r0[1]); bx[tc][2].u[1] = pk2(r0[2], r0[3]);
        bx[tc][2].u[2] = pk2(r1[0], r1[1]); bx[tc][2].u[3] = pk2(r1[2], r1[3]);
        bx[tc][3].u[0] = pk2(r2[0], r2[1]); bx[tc][3].u[1] = pk2(r2[2], r2[3]);
        bx[tc][3].u[2] = pk2(r3[0], r3[1]); bx[tc][3].u[3] = pk2(r3[2], r3[3]);
    }

    // ---- layer 1: Y1T[j][m] = sum_k w1[j][k] * x[m][k] + b1[j] ----
    float4v acc[4][4]; // [tr][tc]; lane holds col c, rows tr*16 + g*4 + i
#pragma unroll
    for (int tr = 0; tr < 4; tr++) {
        float4v bias = *(const float4v*)(b1 + tr * 16 + g * 4);
        Frag a1s[4];
#pragma unroll
        for (int ks = 0; ks < 4; ks++)
            a1s[ks].v = a1p[(tr * 4 + ks) * 64 + lane];
#pragma unroll
        for (int tc = 0; tc < 4; tc++) {
            float4v cacc = bias;
#pragma unroll
            for (int ks = 0; ks < 4; ks++)
                cacc = __builtin_amdgcn_mfma_f32_16x16x32_bf16(
                    a1s[ks].s, bx[tc][ks].s, cacc, 0, 0, 0);
            acc[tr][tc] = cacc;
        }
    }

    // ---- relu + re-layout Y1T C-frags -> B-frags for layer 2 ----
    // dest (tc, ks2, reg r): value j = ks2*32 + g*8 + 2r(+1), col m = tc*16+c.
    // source C tile tr_prev = 2*ks2 + (g>>1), lane (c, g_src=(g&1)*2+(r>>1)).
    Frag b2f[4][2];
#pragma unroll
    for (int tc = 0; tc < 4; tc++) {
        int pk[4][2];
#pragma unroll
        for (int trp = 0; trp < 4; trp++) {
#pragma unroll
            for (int ip = 0; ip < 2; ip++) {
                float lo = fmaxf(acc[trp][tc][2 * ip], 0.0f);
                float hi = fmaxf(acc[trp][tc][2 * ip + 1], 0.0f);
                pk[trp][ip] = pk2(lo, hi);
            }
        }
#pragma unroll
        for (int ks2 = 0; ks2 < 2; ks2++) {
#pragma unroll
            for (int r = 0; r < 4; r++) {
                int srclane = (lane & 15) | ((lane & 16) << 1) | ((r >> 1) << 4);
                int va = __shfl(pk[2 * ks2 + 0][r & 1], srclane);
                int vb = __shfl(pk[2 * ks2 + 1][r & 1], srclane);
                b2f[tc][ks2].u[r] = (lane & 32) ? vb : va;
            }
        }
    }

    // ---- layer 2: Y2T[j][m] = sum_k w2[j][k] * relu(Y1)[m][k] + b2[j] ----
    float4v acc2[4][4];
#pragma unroll
    for (int tr = 0; tr < 4; tr++) {
        float4v bias = *(const float4v*)(b2 + tr * 16 + g * 4);
        Frag a2s[2];
#pragma unroll
        for (int ks = 0; ks < 2; ks++)
            a2s[ks].v = a2p[(tr * 2 + ks) * 64 + lane];
#pragma unroll
        for (int tc = 0; tc < 4; tc++) {
            float4v cacc = bias;
#pragma unroll
            for (int ks = 0; ks < 2; ks++)
                cacc = __builtin_amdgcn_mfma_f32_16x16x32_bf16(
                    a2s[ks].s, b2f[tc][ks].s, cacc, 0, 0, 0);
            acc2[tr][tc] = cacc;
        }
    }

    // ---- layer 3 + sigmoid: s[m] = sum_j relu(y2T[j][m]) * w3[j] + b3 ----
    float4v w3f[4];
#pragma unroll
    for (int tr = 0; tr < 4; tr++)
        w3f[tr] = *(const float4v*)(w3 + tr * 16 + g * 4);
    float b3v = b3[0];

    float pv[4]; // pi for m = tc*16 + c (replicated over g)
#pragma unroll
    for (int tc = 0; tc < 4; tc++) {
        float pt = 0.0f;
#pragma unroll
        for (int tr = 0; tr < 4; tr++) {
#pragma unroll
            for (int i = 0; i < 4; i++)
                pt = fmaf(fmaxf(acc2[tr][tc][i], 0.0f), w3f[tr][i], pt);
        }
        pt += __shfl_xor(pt, 16);
        pt += __shfl_xor(pt, 32);
        pv[tc] = sigmoidf_(pt + b3v);
    }

    // ---- softmax over all 64 m ----
    float mx = fmaxf(fmaxf(pv[0], pv[1]), fmaxf(pv[2], pv[3]));
#pragma unroll
    for (int o = 1; o < 16; o <<= 1) mx = fmaxf(mx, __shfl_xor(mx, o));
    float ex[4];
    float sm = 0.0f;
#pragma unroll
    for (int tc = 0; tc < 4; tc++) { ex[tc] = expf(pv[tc] - mx); sm += ex[tc]; }
#pragma unroll
    for (int o = 1; o < 16; o <<= 1) sm += __shfl_xor(sm, o);
    float inv = 1.0f / sm;
    float p[4];
#pragma unroll
    for (int tc = 0; tc < 4; tc++) p[tc] = ex[tc] * inv;

    // ---- PV: a[d=lane] = sum_m p_m * ent_emb[tail_m][d] ----
    float pa0 = 0.f, pa1 = 0.f, pa2 = 0.f, pa3 = 0.f;
#pragma unroll 4
    for (int m = 0; m < 64; m += 4) {
        float pm0 = __shfl(p[(m + 0) >> 4], (m + 0) & 15);
        float pm1 = __shfl(p[(m + 1) >> 4], (m + 1) & 15);
        float pm2 = __shfl(p[(m + 2) >> 4], (m + 2) & 15);
        float pm3 = __shfl(p[(m + 3) >> 4], (m + 3) & 15);
        int tm0 = __shfl(tidx, m + 0), tm1 = __shfl(tidx, m + 1);
        int tm2 = __shfl(tidx, m + 2), tm3 = __shfl(tidx, m + 3);
        pa0 = fmaf(pm0, ent_emb[(size_t)tm0 * 64 + lane], pa0);
        pa1 = fmaf(pm1, ent_emb[(size_t)tm1 * 64 + lane], pa1);
        pa2 = fmaf(pm2, ent_emb[(size_t)tm2 * 64 + lane], pa2);
        pa3 = fmaf(pm3, ent_emb[(size_t)tm3 * 64 + lane], pa3);
    }
    e_parts[((side * 3 + (l + 1)) * BB + b) * 64 + lane] =
        pa0 + pa1 + pa2 + pa3;
}

// final: per b, user/item agg MLP + dot + sigmoid
__global__ __launch_bounds__(256) void final_kernel(
    const float* __restrict__ bagg, const float* __restrict__ wsF,
    float* __restrict__ out) {
    const float* waggT = wsF + OFF_WAGGT;
    const float* ep = wsF + OFF_EP;
    int b = blockIdx.x * 4 + (threadIdx.x >> 6);
    int lane = threadIdx.x & 63;
    float eu[3], ev[3];
#pragma unroll
    for (int cc = 0; cc < 3; cc++) {
        eu[cc] = ep[((0 * 3 + cc) * BB + b) * 64 + lane];
        ev[cc] = ep[((1 * 3 + cc) * BB + b) * 64 + lane];
    }
    float us = bagg[lane], it = bagg[lane];
#pragma unroll
    for (int k = 0; k < 192; k++) {
        float w = waggT[k * 64 + lane];
        us = fmaf(__shfl(eu[k >> 6], k & 63), w, us);
        it = fmaf(__shfl(ev[k >> 6], k & 63), w, it);
    }
    us = sigmoidf_(us);
    it = sigmoidf_(it);
    float prod = us * it;
#pragma unroll
    for (int o = 32; o > 0; o >>= 1) prod += __shfl_xor(prod, o);
    if (lane == 0) out[b] = sigmoidf_(prod);
}

extern "C" void kernel_launch(void* const* d_in, const int* in_sizes, int n_in,
                              void* d_out, int out_size, void* d_ws, size_t ws_size,
                              hipStream_t stream) {
    const float* ent_emb = (const float*)d_in[0];
    const float* rec_emb = (const float*)d_in[1];
    const float* rel_emb = (const float*)d_in[2];
    const float* w1   = (const float*)d_in[3];
    const float* b1   = (const float*)d_in[4];
    const float* w2   = (const float*)d_in[5];
    const float* b2   = (const float*)d_in[6];
    const float* w3   = (const float*)d_in[7];
    const float* b3   = (const float*)d_in[8];
    const float* wagg = (const float*)d_in[9];
    const float* bagg = (const float*)d_in[10];
    const int* u_ent   = (const int*)d_in[11];
    const int* u_heads = (const int*)d_in[12];
    const int* u_rels  = (const int*)d_in[13];
    const int* u_tails = (const int*)d_in[14];
    const int* v_ent   = (const int*)d_in[15];
    const int* v_heads = (const int*)d_in[16];
    const int* v_rels  = (const int*)d_in[17];
    const int* v_tails = (const int*)d_in[18];

    int* wsI = (int*)d_ws;
    float* wsF = (float*)d_ws;
    float* e_parts = wsF + OFF_EP;
    float* out = (float*)d_out;

    prep_kernel<<<48, 256, 0, stream>>>(w1, w2, wagg, wsI);
    hop0_kernel<<<1024, 256, 0, stream>>>(ent_emb, rec_emb, u_ent, v_ent, e_parts);
    attn_kernel<<<2048, 256, 0, stream>>>(ent_emb, rel_emb, b1, b2, w3, b3,
                                          u_heads, u_rels, u_tails,
                                          v_heads, v_rels, v_tails,
                                          wsI, e_parts);
    final_kernel<<<512, 256, 0, stream>>>(bagg, wsF, out);
}